// Round 8
// baseline (153.255 us; speedup 1.0000x reference)
//
#include <hip/hip_runtime.h>
#include <math.h>

#define BB 4
#define NN 2048
#define F_IN 128
#define HH 4
#define CC 32
#define HC 128
#define NEG_SLOPE 0.2f
#define CAP 64          // per-row list cap (max degree ~46 incl self-loop)
#define RT 64           // row-tile
#define CT 128          // col-tile
#define NRT 32          // NN/RT
#define NCT 16          // NN/CT
#define LCAP 320        // per-tile edge cap (avg ~86, ~26 sigma margin)

__device__ __forceinline__ float lrelu(float v) {
    return v > 0.f ? v : NEG_SLOPE * v;
}

// ---- K1: feat = x@W + att logits (R6 structure: 512 blocks, broadcast b128) ----
__global__ __launch_bounds__(256) void k_gemm_att(const float* __restrict__ x,
                                                  const float* __restrict__ W,
                                                  const float* __restrict__ att_src,
                                                  const float* __restrict__ att_dst,
                                                  float* __restrict__ feat,
                                                  float* __restrict__ a_src,
                                                  float* __restrict__ a_dst,
                                                  int* __restrict__ cnt) {
    __shared__ float xs[F_IN][20];     // [k][row]; quads at rows 0/4/8/12 16B-aligned
    __shared__ float fs[16][HC + 1];
    const long row0 = (long)blockIdx.x * 16;
    const int t = threadIdx.x;
    for (int idx = t; idx < 16 * F_IN; idx += 256) {
        const int row = idx >> 7, k = idx & 127;
        xs[k][row] = x[row0 * F_IN + idx];
    }
    __syncthreads();
    const int col = t & 127;
    const int rg  = (t >> 7) * 8;      // 0 or 8; constant within a wave -> broadcast reads
    float acc[8];
#pragma unroll
    for (int r = 0; r < 8; ++r) acc[r] = 0.f;
#pragma unroll 4
    for (int k = 0; k < F_IN; ++k) {
        const float w = W[k * HC + col];
        const float4 xa = *(const float4*)&xs[k][rg];
        const float4 xb = *(const float4*)&xs[k][rg + 4];
        acc[0] += xa.x * w; acc[1] += xa.y * w; acc[2] += xa.z * w; acc[3] += xa.w * w;
        acc[4] += xb.x * w; acc[5] += xb.y * w; acc[6] += xb.z * w; acc[7] += xb.w * w;
    }
#pragma unroll
    for (int r = 0; r < 8; ++r) {
        feat[(row0 + rg + r) * HC + col] = acc[r];
        fs[rg + r][col] = acc[r];
    }
    __syncthreads();
    if (t < 64) {
        const int row = t & 15;
        const int h   = t >> 4;
        float s = 0.f, d = 0.f;
#pragma unroll
        for (int c = 0; c < CC; ++c) {
            const float v = fs[row][h * CC + c];
            s += v * att_src[h * CC + c];
            d += v * att_dst[h * CC + c];
        }
        a_src[(row0 + row) * 4 + h] = s;
        a_dst[(row0 + row) * 4 + h] = d;
    }
    if (t < 16) cnt[blockIdx.x * 16 + t] = 0;
}

// ---- K2: 64x128 tile scan (R5 structure); partial now [b][j][rt] transposed ----
__global__ __launch_bounds__(256) void k_tile(const float4* __restrict__ adj4,
                                              const float4* __restrict__ as4g,
                                              const float4* __restrict__ ad4g,
                                              int* __restrict__ cnt,
                                              unsigned short* __restrict__ nbr,
                                              float4* __restrict__ partial) {
    const int bx = blockIdx.x;          // B * NRT * NCT = 2048
    const int b  = bx >> 9;
    const int rt = (bx >> 4) & 31;
    const int ct = bx & 15;
    const int i0 = rt * RT;
    const int c0 = ct * CT;
    const int t  = threadIdx.x;

    __shared__ float4 as4[RT];
    __shared__ float4 ad4[CT];
    __shared__ float4 pd[CT];
    __shared__ unsigned short blist[LCAP];
    __shared__ int rowcnt[RT];
    __shared__ int rowoff[RT];
    __shared__ int nent;

    const float4* p = adj4 + ((long)((b << 11) + i0) + (t >> 5)) * (NN / 4)
                    + (c0 >> 2) + (t & 31);
    float4 v[8];
#pragma unroll
    for (int s = 0; s < 8; ++s)
        v[s] = p[s * 8 * (NN / 4)];

    if (t < RT) {
        as4[t] = as4g[(b << 11) + i0 + t];
        rowcnt[t] = 0;
    }
    if (t < CT) {
        ad4[t] = ad4g[(b << 11) + c0 + t];
        pd[t] = make_float4(0.f, 0.f, 0.f, 0.f);
    }
    if (t == 0) nent = 0;
    __syncthreads();

    const int jb = (t & 31) * 4;
    const int rl = t >> 5;
#pragma unroll
    for (int s = 0; s < 8; ++s) {
        const int il = s * 8 + rl;
        const int gi = i0 + il;
#pragma unroll
        for (int k = 0; k < 4; ++k) {
            const float vv = (&v[s].x)[k];
            if (vv != 0.f || gi == c0 + jb + k) {
                int pos = atomicAdd(&nent, 1);
                if (pos < LCAP)
                    blist[pos] = (unsigned short)((il << 7) | (jb + k));
                atomicAdd(&rowcnt[il], 1);
            }
        }
    }
    __syncthreads();

    if (t < RT) {
        int rc = rowcnt[t];
        int bs = 0;
        if (rc > 0) bs = atomicAdd(&cnt[(b << 11) + i0 + t], rc);
        rowoff[t] = bs;
    }
    __syncthreads();

    const int ne = min(nent, LCAP);
    for (int e = t; e < ne; e += 256) {
        const int pk = blist[e];
        const int il = pk >> 7;
        const int jl = pk & 127;
        const float4 s4 = as4[il];
        const float4 d4 = ad4[jl];
        atomicAdd(&(&pd[jl].x)[0], __expf(lrelu(s4.x + d4.x)));
        atomicAdd(&(&pd[jl].x)[1], __expf(lrelu(s4.y + d4.y)));
        atomicAdd(&(&pd[jl].x)[2], __expf(lrelu(s4.z + d4.z)));
        atomicAdd(&(&pd[jl].x)[3], __expf(lrelu(s4.w + d4.w)));
        int slot = atomicAdd(&rowoff[il], 1);
        if (slot < CAP)
            nbr[((long)((b << 11) + i0 + il)) * CAP + slot] = (unsigned short)(c0 + jl);
    }
    __syncthreads();

    // transposed write: partial[(b, j, rt)] so K3 can read rt-partials coalesced
    if (t < CT)
        partial[((((long)(b << 11)) + c0 + t) << 5) + rt] = pd[t];
}

// ---- K3: fused rdenom + aggregation. 32-lane coalesced partial gather +
//      shuffle reduce, then 8-accumulator sparse gather. ----
__global__ __launch_bounds__(128) void k_aggr(const float* __restrict__ feat,
                                              const float* __restrict__ a_src,
                                              const float4* __restrict__ ad4,
                                              const float4* __restrict__ partial,
                                              const int* __restrict__ cnt,
                                              const unsigned short* __restrict__ nbr,
                                              const float* __restrict__ bias,
                                              float* __restrict__ out) {
    const int bi = blockIdx.x;
    const int b  = bi >> 11;
    const int t  = threadIdx.x;
    __shared__ float4 s_coef[CAP];
    __shared__ float4 s_rd[CAP];
    __shared__ int    s_j[CAP];
    __shared__ float  s_as[4];
    const int n = min(cnt[bi], CAP);
    if (t < 4) s_as[t] = a_src[bi * 4 + t];
    if (t < n) s_j[t] = nbr[(long)bi * CAP + t];
    __syncthreads();

    // denom reduce: group g of 32 lanes handles nbr s = g, g+4, ...
    const int g = t >> 5, r = t & 31;
    for (int s = g; s < n; s += 4) {
        const int j = s_j[s];
        float4 p = partial[((((long)(b << 11)) + j) << 5) + r];   // coalesced 512B
#pragma unroll
        for (int off = 16; off; off >>= 1) {
            p.x += __shfl_down(p.x, off, 32);
            p.y += __shfl_down(p.y, off, 32);
            p.z += __shfl_down(p.z, off, 32);
            p.w += __shfl_down(p.w, off, 32);
        }
        if (r == 0)
            s_rd[s] = make_float4(1.f / p.x, 1.f / p.y, 1.f / p.z, 1.f / p.w);
    }
    __syncthreads();

    if (t < n) {
        const int j = s_j[t];
        const float4 ad = ad4[(b << 11) + j];
        const float4 rd = s_rd[t];
        float4 c;
        c.x = __expf(lrelu(s_as[0] + ad.x)) * rd.x;
        c.y = __expf(lrelu(s_as[1] + ad.y)) * rd.y;
        c.z = __expf(lrelu(s_as[2] + ad.z)) * rd.z;
        c.w = __expf(lrelu(s_as[3] + ad.w)) * rd.w;
        s_coef[t] = c;
    }
    __syncthreads();

    const int h = t >> 5;
    const float* fb = feat + ((long)(b << 11)) * HC + t;
    float a0 = 0.f, a1 = 0.f, a2 = 0.f, a3 = 0.f;
    float a4 = 0.f, a5 = 0.f, a6 = 0.f, a7 = 0.f;
    int s = 0;
    for (; s + 8 <= n; s += 8) {
        const int j0 = s_j[s + 0], j1 = s_j[s + 1], j2 = s_j[s + 2], j3 = s_j[s + 3];
        const int j4 = s_j[s + 4], j5 = s_j[s + 5], j6 = s_j[s + 6], j7 = s_j[s + 7];
        a0 += (&s_coef[s + 0].x)[h] * fb[(long)j0 * HC];
        a1 += (&s_coef[s + 1].x)[h] * fb[(long)j1 * HC];
        a2 += (&s_coef[s + 2].x)[h] * fb[(long)j2 * HC];
        a3 += (&s_coef[s + 3].x)[h] * fb[(long)j3 * HC];
        a4 += (&s_coef[s + 4].x)[h] * fb[(long)j4 * HC];
        a5 += (&s_coef[s + 5].x)[h] * fb[(long)j5 * HC];
        a6 += (&s_coef[s + 6].x)[h] * fb[(long)j6 * HC];
        a7 += (&s_coef[s + 7].x)[h] * fb[(long)j7 * HC];
    }
    for (; s < n; ++s)
        a0 += (&s_coef[s].x)[h] * fb[(long)s_j[s] * HC];
    out[(long)bi * HC + t] = ((a0 + a1) + (a2 + a3)) + ((a4 + a5) + (a6 + a7)) + bias[t];
}

extern "C" void kernel_launch(void* const* d_in, const int* in_sizes, int n_in,
                              void* d_out, int out_size, void* d_ws, size_t ws_size,
                              hipStream_t stream) {
    const float* x       = (const float*)d_in[0];
    const float* adj     = (const float*)d_in[1];
    const float* W       = (const float*)d_in[2];
    const float* att_src = (const float*)d_in[3];
    const float* att_dst = (const float*)d_in[4];
    const float* bias    = (const float*)d_in[5];
    float* out = (float*)d_out;

    float* feat    = (float*)d_ws;                              // 4 MB
    float* a_src   = feat    + (long)BB * NN * HC;              // 128 KB
    float* a_dst   = a_src   + (long)BB * NN * HH;              // 128 KB
    float* partial = a_dst   + (long)BB * NN * HH;              // B*N*NRT float4 = 4 MB
    int*   cnt     = (int*)(partial + (long)BB * NN * NRT * 4); // 32 KB
    unsigned short* nbr = (unsigned short*)(cnt + (long)BB * NN);   // 1 MB

    k_gemm_att<<<(BB * NN) / 16, 256, 0, stream>>>(x, W, att_src, att_dst,
                                                   feat, a_src, a_dst, cnt);
    k_tile<<<BB * NRT * NCT, 256, 0, stream>>>((const float4*)adj, (const float4*)a_src,
                                               (const float4*)a_dst, cnt, nbr,
                                               (float4*)partial);
    k_aggr<<<BB * NN, 128, 0, stream>>>(feat, a_src, (const float4*)a_dst,
                                        (const float4*)partial, cnt, nbr, bias, out);
}

// Round 9
// 141.339 us; speedup vs baseline: 1.0843x; 1.0843x over previous
//
#include <hip/hip_runtime.h>
#include <math.h>

#define BB 4
#define NN 2048
#define F_IN 128
#define HH 4
#define CC 32
#define HC 128
#define NEG_SLOPE 0.2f
#define CAP 64          // per-row list cap (max degree ~46 incl self-loop)
#define RT 64           // row-tile
#define CT 128          // col-tile
#define NRT 32          // NN/RT
#define NCT 16          // NN/CT
#define LCAP 320        // per-tile edge cap (avg ~86, ~26 sigma margin)

__device__ __forceinline__ float lrelu(float v) {
    return v > 0.f ? v : NEG_SLOPE * v;
}

// ---- K1: feat = x@W + att logits. 16 rows/block, thread = 4col x 2row:
//      per k per wave: 1 ds_read_b64 + 1 coalesced W float4 + 8 FMA (VALU-bound) ----
__global__ __launch_bounds__(256) void k_gemm_att(const float* __restrict__ x,
                                                  const float* __restrict__ W,
                                                  const float* __restrict__ att_src,
                                                  const float* __restrict__ att_dst,
                                                  float* __restrict__ feat,
                                                  float* __restrict__ a_src,
                                                  float* __restrict__ a_dst,
                                                  int* __restrict__ cnt) {
    __shared__ float xs[F_IN][18];     // [k][row], 16 rows + pad 2 (b64-aligned, 2-way max)
    __shared__ float fs[16][HC + 1];
    const long row0 = (long)blockIdx.x * 16;
    const int t = threadIdx.x;
    for (int idx = t; idx < 16 * F_IN; idx += 256)
        xs[idx & 127][idx >> 7] = x[row0 * F_IN + idx];
    __syncthreads();

    const int c4 = (t & 31) * 4;       // 4 consecutive cols
    const int rg = (t >> 5) * 2;       // 2 consecutive rows
    float acc[2][4];
#pragma unroll
    for (int r = 0; r < 2; ++r)
#pragma unroll
        for (int c = 0; c < 4; ++c) acc[r][c] = 0.f;

#pragma unroll 4
    for (int k = 0; k < F_IN; ++k) {
        const float4 w = *(const float4*)(W + k * HC + c4);
        const float2 xv = *(const float2*)&xs[k][rg];
        acc[0][0] += xv.x * w.x; acc[0][1] += xv.x * w.y;
        acc[0][2] += xv.x * w.z; acc[0][3] += xv.x * w.w;
        acc[1][0] += xv.y * w.x; acc[1][1] += xv.y * w.y;
        acc[1][2] += xv.y * w.z; acc[1][3] += xv.y * w.w;
    }

#pragma unroll
    for (int r = 0; r < 2; ++r) {
        const int row = rg + r;
        *(float4*)&feat[(row0 + row) * HC + c4] =
            make_float4(acc[r][0], acc[r][1], acc[r][2], acc[r][3]);
        fs[row][c4 + 0] = acc[r][0];
        fs[row][c4 + 1] = acc[r][1];
        fs[row][c4 + 2] = acc[r][2];
        fs[row][c4 + 3] = acc[r][3];
    }
    __syncthreads();

    if (t < 64) {
        const int row = t & 15;
        const int h   = t >> 4;
        float s = 0.f, d = 0.f;
#pragma unroll
        for (int c = 0; c < CC; ++c) {
            const float v = fs[row][h * CC + c];
            s += v * att_src[h * CC + c];
            d += v * att_dst[h * CC + c];
        }
        a_src[(row0 + row) * 4 + h] = s;
        a_dst[(row0 + row) * 4 + h] = d;
    }
    if (t < 16) cnt[blockIdx.x * 16 + t] = 0;
}

// ---- K2: 64x128 tile scan; loads up front, blist compaction (R5 best) ----
__global__ __launch_bounds__(256) void k_tile(const float4* __restrict__ adj4,
                                              const float4* __restrict__ as4g,
                                              const float4* __restrict__ ad4g,
                                              int* __restrict__ cnt,
                                              unsigned short* __restrict__ nbr,
                                              float4* __restrict__ partial) {
    const int bx = blockIdx.x;          // B * NRT * NCT = 2048
    const int b  = bx >> 9;
    const int rt = (bx >> 4) & 31;
    const int ct = bx & 15;
    const int i0 = rt * RT;
    const int c0 = ct * CT;
    const int t  = threadIdx.x;

    __shared__ float4 as4[RT];
    __shared__ float4 ad4[CT];
    __shared__ float4 pd[CT];
    __shared__ unsigned short blist[LCAP];
    __shared__ int rowcnt[RT];
    __shared__ int rowoff[RT];
    __shared__ int nent;

    const float4* p = adj4 + ((long)((b << 11) + i0) + (t >> 5)) * (NN / 4)
                    + (c0 >> 2) + (t & 31);
    float4 v[8];
#pragma unroll
    for (int s = 0; s < 8; ++s)
        v[s] = p[s * 8 * (NN / 4)];

    if (t < RT) {
        as4[t] = as4g[(b << 11) + i0 + t];
        rowcnt[t] = 0;
    }
    if (t < CT) {
        ad4[t] = ad4g[(b << 11) + c0 + t];
        pd[t] = make_float4(0.f, 0.f, 0.f, 0.f);
    }
    if (t == 0) nent = 0;
    __syncthreads();

    const int jb = (t & 31) * 4;
    const int rl = t >> 5;
#pragma unroll
    for (int s = 0; s < 8; ++s) {
        const int il = s * 8 + rl;
        const int gi = i0 + il;
#pragma unroll
        for (int k = 0; k < 4; ++k) {
            const float vv = (&v[s].x)[k];
            if (vv != 0.f || gi == c0 + jb + k) {
                int pos = atomicAdd(&nent, 1);
                if (pos < LCAP)
                    blist[pos] = (unsigned short)((il << 7) | (jb + k));
                atomicAdd(&rowcnt[il], 1);
            }
        }
    }
    __syncthreads();

    if (t < RT) {
        int rc = rowcnt[t];
        int bs = 0;
        if (rc > 0) bs = atomicAdd(&cnt[(b << 11) + i0 + t], rc);
        rowoff[t] = bs;
    }
    __syncthreads();

    const int ne = min(nent, LCAP);
    for (int e = t; e < ne; e += 256) {
        const int pk = blist[e];
        const int il = pk >> 7;
        const int jl = pk & 127;
        const float4 s4 = as4[il];
        const float4 d4 = ad4[jl];
        atomicAdd(&(&pd[jl].x)[0], __expf(lrelu(s4.x + d4.x)));
        atomicAdd(&(&pd[jl].x)[1], __expf(lrelu(s4.y + d4.y)));
        atomicAdd(&(&pd[jl].x)[2], __expf(lrelu(s4.z + d4.z)));
        atomicAdd(&(&pd[jl].x)[3], __expf(lrelu(s4.w + d4.w)));
        int slot = atomicAdd(&rowoff[il], 1);
        if (slot < CAP)
            nbr[((long)((b << 11) + i0 + il)) * CAP + slot] = (unsigned short)(c0 + jl);
    }
    __syncthreads();

    if (t < CT)
        partial[((long)(b * NRT + rt) << 11) + c0 + t] = pd[t];
}

// ---- K3: reduce partials over 32 row-tiles, store reciprocal ----
__global__ __launch_bounds__(256) void k_rdenom(const float4* __restrict__ partial,
                                                float4* __restrict__ rdenom) {
    const int u = blockIdx.x * blockDim.x + threadIdx.x;   // over B*N
    if (u >= BB * NN) return;
    const int b = u >> 11;
    const int j = u & 2047;
    float4 s = make_float4(0.f, 0.f, 0.f, 0.f);
#pragma unroll
    for (int rt = 0; rt < NRT; ++rt) {
        const float4 p = partial[((long)(b * NRT + rt) << 11) + j];
        s.x += p.x; s.y += p.y; s.z += p.z; s.w += p.w;
    }
    rdenom[u] = make_float4(1.f / s.x, 1.f / s.y, 1.f / s.z, 1.f / s.w);
}

// ---- K4: sparse aggregation, coef = e * rdenom, 8 accumulators for ILP ----
__global__ __launch_bounds__(128) void k_aggr(const float* __restrict__ feat,
                                              const float* __restrict__ a_src,
                                              const float4* __restrict__ ad4,
                                              const float4* __restrict__ rd4,
                                              const int* __restrict__ cnt,
                                              const unsigned short* __restrict__ nbr,
                                              const float* __restrict__ bias,
                                              float* __restrict__ out) {
    const int bi = blockIdx.x;
    const int b  = bi >> 11;
    const int t  = threadIdx.x;
    __shared__ float4 s_coef[CAP];
    __shared__ int    s_j[CAP];
    __shared__ float  s_as[4];
    const int n = min(cnt[bi], CAP);
    if (t < 4) s_as[t] = a_src[bi * 4 + t];
    if (t < n) s_j[t] = nbr[(long)bi * CAP + t];
    __syncthreads();
    if (t < n) {
        const int j = s_j[t];
        const float4 ad = ad4[(b << 11) + j];
        const float4 rd = rd4[(b << 11) + j];
        float4 c;
        c.x = __expf(lrelu(s_as[0] + ad.x)) * rd.x;
        c.y = __expf(lrelu(s_as[1] + ad.y)) * rd.y;
        c.z = __expf(lrelu(s_as[2] + ad.z)) * rd.z;
        c.w = __expf(lrelu(s_as[3] + ad.w)) * rd.w;
        s_coef[t] = c;
    }
    __syncthreads();
    const int h = t >> 5;
    const float* fb = feat + ((long)(b << 11)) * HC + t;
    float a0 = 0.f, a1 = 0.f, a2 = 0.f, a3 = 0.f;
    float a4 = 0.f, a5 = 0.f, a6 = 0.f, a7 = 0.f;
    int s = 0;
    for (; s + 8 <= n; s += 8) {
        const int j0 = s_j[s + 0], j1 = s_j[s + 1], j2 = s_j[s + 2], j3 = s_j[s + 3];
        const int j4 = s_j[s + 4], j5 = s_j[s + 5], j6 = s_j[s + 6], j7 = s_j[s + 7];
        a0 += (&s_coef[s + 0].x)[h] * fb[(long)j0 * HC];
        a1 += (&s_coef[s + 1].x)[h] * fb[(long)j1 * HC];
        a2 += (&s_coef[s + 2].x)[h] * fb[(long)j2 * HC];
        a3 += (&s_coef[s + 3].x)[h] * fb[(long)j3 * HC];
        a4 += (&s_coef[s + 4].x)[h] * fb[(long)j4 * HC];
        a5 += (&s_coef[s + 5].x)[h] * fb[(long)j5 * HC];
        a6 += (&s_coef[s + 6].x)[h] * fb[(long)j6 * HC];
        a7 += (&s_coef[s + 7].x)[h] * fb[(long)j7 * HC];
    }
    for (; s < n; ++s)
        a0 += (&s_coef[s].x)[h] * fb[(long)s_j[s] * HC];
    out[(long)bi * HC + t] = ((a0 + a1) + (a2 + a3)) + ((a4 + a5) + (a6 + a7)) + bias[t];
}

extern "C" void kernel_launch(void* const* d_in, const int* in_sizes, int n_in,
                              void* d_out, int out_size, void* d_ws, size_t ws_size,
                              hipStream_t stream) {
    const float* x       = (const float*)d_in[0];
    const float* adj     = (const float*)d_in[1];
    const float* W       = (const float*)d_in[2];
    const float* att_src = (const float*)d_in[3];
    const float* att_dst = (const float*)d_in[4];
    const float* bias    = (const float*)d_in[5];
    float* out = (float*)d_out;

    float* feat    = (float*)d_ws;                              // 4 MB
    float* a_src   = feat    + (long)BB * NN * HC;
    float* a_dst   = a_src   + (long)BB * NN * HH;
    float* rdenom  = a_dst   + (long)BB * NN * HH;
    float* partial = rdenom  + (long)BB * NN * HH;              // 4 MB
    int*   cnt     = (int*)(partial + (long)BB * NRT * NN * HH);
    unsigned short* nbr = (unsigned short*)(cnt + (long)BB * NN);   // B*N*CAP u16

    k_gemm_att<<<(BB * NN) / 16, 256, 0, stream>>>(x, W, att_src, att_dst,
                                                   feat, a_src, a_dst, cnt);
    k_tile<<<BB * NRT * NCT, 256, 0, stream>>>((const float4*)adj, (const float4*)a_src,
                                               (const float4*)a_dst, cnt, nbr,
                                               (float4*)partial);
    k_rdenom<<<(BB * NN + 255) / 256, 256, 0, stream>>>((const float4*)partial,
                                                        (float4*)rdenom);
    k_aggr<<<BB * NN, 128, 0, stream>>>(feat, a_src, (const float4*)a_dst,
                                        (const float4*)rdenom, cnt, nbr, bias, out);
}